// Round 2
// baseline (728.189 us; speedup 1.0000x reference)
//
#include <hip/hip_runtime.h>
#include <hip/hip_bf16.h>

#define Bdim 256
#define Ddim 1024
#define Hdim 2048
#define Tdim 100
#define BH (Bdim*Hdim)            // 524288
#define M3 ((Tdim-1)*Bdim)        // 25344

#define OUT_MEM ((size_t)BH)                          // mem_rec starts after out0
#define OUT_SPK ((size_t)BH + (size_t)Tdim*2*BH)      // spk_rec after mem_rec

typedef __attribute__((ext_vector_type(8))) short short8;
typedef __attribute__((ext_vector_type(4))) float f32x4;

// async global->LDS, 16B per lane, LDS dest = wave-uniform base + lane*16
#define GLD16(g, l) __builtin_amdgcn_global_load_lds( \
    (__attribute__((address_space(1))) void*)(g), \
    (__attribute__((address_space(3))) void*)(l), 16, 0, 0)

// ---------------- K1: ns0 = X @ W0 (fp32, computed once) ----------------
// 512 threads: 128 blocks x 8 waves = 1024 waves -> every SIMD busy.
__global__ __launch_bounds__(512) void k1_ns0(const float* __restrict__ X,
                                              const float* __restrict__ W0,
                                              float* __restrict__ NS0) {
  __shared__ float As[16][65];
  __shared__ float Bs[16][65];
  int tid = threadIdx.x;
  int tm = tid >> 4;      // 0..31 -> 2 rows each
  int tn = tid & 15;      // 0..15 -> 4 cols each
  int bm = blockIdx.x * 64, bn = blockIdx.y * 64;
  float acc[2][4] = {};
  for (int k0 = 0; k0 < Ddim; k0 += 16) {
    for (int i = tid; i < 64*16; i += 512) {
      int m = i >> 4, k = i & 15;
      As[k][m] = X[(size_t)(bm + m)*Ddim + k0 + k];
    }
    for (int i = tid; i < 16*64; i += 512) {
      int k = i >> 6, n = i & 63;
      Bs[k][n] = W0[(size_t)(k0 + k)*Hdim + bn + n];
    }
    __syncthreads();
    #pragma unroll
    for (int k = 0; k < 16; ++k) {
      float a0 = As[k][tm*2], a1 = As[k][tm*2+1];
      float b[4];
      #pragma unroll
      for (int j = 0; j < 4; ++j) b[j] = Bs[k][tn*4+j];
      #pragma unroll
      for (int j = 0; j < 4; ++j) {
        acc[0][j] = fmaf(a0, b[j], acc[0][j]);
        acc[1][j] = fmaf(a1, b[j], acc[1][j]);
      }
    }
    __syncthreads();
  }
  for (int i = 0; i < 2; ++i)
    for (int j = 0; j < 4; ++j)
      NS0[(size_t)(bm + tm*2 + i)*Hdim + bn + tn*4 + j] = acc[i][j];
}

// ---------------- K2b: W1T[n][k] = bf16(W1[k][n]) ----------------
__global__ __launch_bounds__(256) void k2b_tr(const float* __restrict__ W1,
                                              unsigned short* __restrict__ W1T) {
  __shared__ unsigned short tile[32][33];
  int bk = blockIdx.x*32, bn = blockIdx.y*32;
  int tx = threadIdx.x & 31, ty = threadIdx.x >> 5;
  for (int r = ty; r < 32; r += 8) {
    float f = W1[(size_t)(bk + r)*Hdim + bn + tx];
    __hip_bfloat16 h = __float2bfloat16(f);
    tile[r][tx] = *reinterpret_cast<unsigned short*>(&h);
  }
  __syncthreads();
  for (int r = ty; r < 32; r += 8) {
    W1T[(size_t)(bn + r)*Hdim + bk + tx] = tile[tx][r];
  }
}

// ---------------- K2: layer-0 sim; writes mem0_rec, spk_rec, t=0 zeros, bf16 Z ----------------
__global__ __launch_bounds__(256) void k2_sim(const float* __restrict__ NS0,
                                              float* __restrict__ out,
                                              unsigned short* __restrict__ Zb) {
  size_t idx = (size_t)blockIdx.x*256 + threadIdx.x;  // b*H + j
  float ns = NS0[idx];
  float* mem = out + OUT_MEM;
  float* spk = out + OUT_SPK;
  mem[idx] = 0.f;          // mem_rec[0][0]
  mem[BH + idx] = 0.f;     // mem_rec[0][1]
  spk[idx] = 0.f;          // spk_rec[0]
  float m = 0.f;
  for (int t = 1; t < Tdim; ++t) {
    m = __fadd_rn(__fmul_rn(0.9f, m), ns);   // match numpy's mul-then-add rounding
    bool sp = m > 1.0f;                       // mthr > 0
    float z = sp ? 1.f : 0.f;
    if (sp) m = 0.f;                          // reset, recorded post-reset
    mem[(size_t)(2*t)*BH + idx] = m;
    spk[(size_t)t*BH + idx] = z;
    Zb[(size_t)(t-1)*BH + idx] = sp ? (unsigned short)0x3F80 : (unsigned short)0;
  }
}

// ---------------- K3: C[25344,2048] = Z @ W1, fp32 C scattered into mem_rec[t][1] ----------------
// m97 structure: 128x128 tile, BK=32, linear LDS, global_load_lds width 16.
#define K3_BM 128
#define K3_BN 128
#define K3_BK 32

__global__ __launch_bounds__(256) void k3_gemm(const unsigned short* __restrict__ A,   // Zb [M3][2048]
                                               const unsigned short* __restrict__ BT,  // W1T [2048][2048]
                                               float* __restrict__ mem1) {             // out + OUT_MEM
  __shared__ short As[K3_BM*K3_BK];  // 8 KB, row-major [m][k]
  __shared__ short Bs[K3_BN*K3_BK];  // 8 KB, row-major [n][k]
  int tid = threadIdx.x;
  int l = tid & 63;
  int w = tid >> 6;                       // wave 0..3
  int wr = (w >> 1) << 6, wc = (w & 1) << 6;   // 2x2 waves, 64x64 each
  int lr = l & 15, lg = l >> 4;
  size_t gm = (size_t)blockIdx.x * K3_BM;
  size_t gn = (size_t)blockIdx.y * K3_BN;

  // staging: 8 chunks of 1KB per operand (16 rows x 32k bf16); wave w owns chunks {2w,2w+1}
  int c0 = w*2, c1 = w*2 + 1;
  const unsigned short* a0 = &A [(gm + c0*16 + (l>>2))*Hdim + (l&3)*8];
  const unsigned short* a1 = &A [(gm + c1*16 + (l>>2))*Hdim + (l&3)*8];
  const unsigned short* b0 = &BT[(gn + c0*16 + (l>>2))*Hdim + (l&3)*8];
  const unsigned short* b1 = &BT[(gn + c1*16 + (l>>2))*Hdim + (l&3)*8];
  short* la0 = &As[c0*16*K3_BK];   // wave-uniform LDS bases
  short* la1 = &As[c1*16*K3_BK];
  short* lb0 = &Bs[c0*16*K3_BK];
  short* lb1 = &Bs[c1*16*K3_BK];

  f32x4 acc[4][4] = {};

  for (int k0 = 0; k0 < Hdim; k0 += K3_BK) {
    GLD16(a0 + k0, la0);
    GLD16(a1 + k0, la1);
    GLD16(b0 + k0, lb0);
    GLD16(b1 + k0, lb1);
    __syncthreads();   // compiler drains vmcnt before s_barrier
    short8 af[4], bfr[4];
    #pragma unroll
    for (int mi = 0; mi < 4; ++mi)
      af[mi] = *reinterpret_cast<const short8*>(&As[(wr + mi*16 + lr)*K3_BK + lg*8]);
    #pragma unroll
    for (int ni = 0; ni < 4; ++ni)
      bfr[ni] = *reinterpret_cast<const short8*>(&Bs[(wc + ni*16 + lr)*K3_BK + lg*8]);
    #pragma unroll
    for (int mi = 0; mi < 4; ++mi)
      #pragma unroll
      for (int ni = 0; ni < 4; ++ni)
        acc[mi][ni] = __builtin_amdgcn_mfma_f32_16x16x32_bf16(af[mi], bfr[ni], acc[mi][ni], 0, 0, 0);
    __syncthreads();
  }
  // epilogue: C/D layout col=lane&15, row=(lane>>4)*4+q; scatter fp32 into mem_rec[t][1]
  #pragma unroll
  for (int mi = 0; mi < 4; ++mi)
    #pragma unroll
    for (int ni = 0; ni < 4; ++ni)
      #pragma unroll
      for (int q = 0; q < 4; ++q) {
        int r = (int)gm + wr + mi*16 + lg*4 + q;   // global M row = (t-1)*256 + b
        int trow = r >> 8, b = r & 255;
        size_t col = gn + wc + ni*16 + lr;
        mem1[(size_t)(2*trow + 3)*BH + (size_t)b*Hdim + col] = acc[mi][ni][q];
      }
}

// ---------------- K4: in-place temporal recurrence over C planes -> mem1_rec + out0 ----------------
__global__ __launch_bounds__(256) void k4_rec(float* __restrict__ out) {
  size_t idx = (size_t)blockIdx.x*256 + threadIdx.x;  // b*H + j
  float* mem = out + OUT_MEM;
  float s = 0.f, m = 0.f;
  for (int t = 1; t < Tdim; ++t) {
    float* p = &mem[(size_t)(2*t + 1)*BH + idx];
    float c = *p;                           // C[t-1][b][j] (fp32, exact from MFMA)
    s = __fadd_rn(__fmul_rn(0.95f, s), c);
    m = __fadd_rn(__fmul_rn(0.9f, m), s);
    *p = m;                                 // mem_rec[t][1]
  }
  out[idx] = m;                             // mem1_rec[-1]
}

extern "C" void kernel_launch(void* const* d_in, const int* in_sizes, int n_in,
                              void* d_out, int out_size, void* d_ws, size_t ws_size,
                              hipStream_t stream) {
  const float* X  = (const float*)d_in[0];
  const float* W0 = (const float*)d_in[1];
  const float* W1 = (const float*)d_in[2];
  float* out = (float*)d_out;
  char* ws = (char*)d_ws;

  float*          ns0 = (float*)ws;                                   // 2 MiB
  unsigned short* w1t = (unsigned short*)(ws + (2ull  << 20));        // 8 MiB
  unsigned short* zb  = (unsigned short*)(ws + (10ull << 20));        // 99 MiB (end 109.4 MiB, confirmed fits)

  k1_ns0<<<dim3(Bdim/64, Hdim/64), 512, 0, stream>>>(X, W0, ns0);
  k2b_tr<<<dim3(Hdim/32, Hdim/32), 256, 0, stream>>>(W1, w1t);
  k2_sim<<<dim3(BH/256), 256, 0, stream>>>(ns0, out, zb);
  k3_gemm<<<dim3(M3/K3_BM, Hdim/K3_BN), 256, 0, stream>>>(zb, w1t, out + OUT_MEM);
  k4_rec<<<dim3(BH/256), 256, 0, stream>>>(out);
}

// Round 3
// 629.284 us; speedup vs baseline: 1.1572x; 1.1572x over previous
//
#include <hip/hip_runtime.h>
#include <hip/hip_bf16.h>

#define Bdim 256
#define Ddim 1024
#define Hdim 2048
#define Tdim 100
#define BH (Bdim*Hdim)            // 524288
#define M3 ((Tdim-1)*Bdim)        // 25344

#define OUT_MEM ((size_t)BH)                          // mem_rec starts after out0
#define OUT_SPK ((size_t)BH + (size_t)Tdim*2*BH)      // spk_rec after mem_rec

typedef __attribute__((ext_vector_type(8))) short short8;
typedef __attribute__((ext_vector_type(4))) float f32x4;

// async global->LDS, 16B per lane, LDS dest = wave-uniform base + lane*16
#define GLD16(g, l) __builtin_amdgcn_global_load_lds( \
    (__attribute__((address_space(1))) void*)(g), \
    (__attribute__((address_space(3))) void*)(l), 16, 0, 0)

// ---------------- K1: ns0 = X @ W0 (fp32, computed once) ----------------
__global__ __launch_bounds__(512) void k1_ns0(const float* __restrict__ X,
                                              const float* __restrict__ W0,
                                              float* __restrict__ NS0) {
  __shared__ float As[16][65];
  __shared__ float Bs[16][65];
  int tid = threadIdx.x;
  int tm = tid >> 4;      // 0..31 -> 2 rows each
  int tn = tid & 15;      // 0..15 -> 4 cols each
  int bm = blockIdx.x * 64, bn = blockIdx.y * 64;
  float acc[2][4] = {};
  for (int k0 = 0; k0 < Ddim; k0 += 16) {
    for (int i = tid; i < 64*16; i += 512) {
      int m = i >> 4, k = i & 15;
      As[k][m] = X[(size_t)(bm + m)*Ddim + k0 + k];
    }
    for (int i = tid; i < 16*64; i += 512) {
      int k = i >> 6, n = i & 63;
      Bs[k][n] = W0[(size_t)(k0 + k)*Hdim + bn + n];
    }
    __syncthreads();
    #pragma unroll
    for (int k = 0; k < 16; ++k) {
      float a0 = As[k][tm*2], a1 = As[k][tm*2+1];
      float b[4];
      #pragma unroll
      for (int j = 0; j < 4; ++j) b[j] = Bs[k][tn*4+j];
      #pragma unroll
      for (int j = 0; j < 4; ++j) {
        acc[0][j] = fmaf(a0, b[j], acc[0][j]);
        acc[1][j] = fmaf(a1, b[j], acc[1][j]);
      }
    }
    __syncthreads();
  }
  for (int i = 0; i < 2; ++i)
    for (int j = 0; j < 4; ++j)
      NS0[(size_t)(bm + tm*2 + i)*Hdim + bn + tn*4 + j] = acc[i][j];
}

// ---------------- K2b: W1T[n][k] = bf16(W1[k][n]) ----------------
__global__ __launch_bounds__(256) void k2b_tr(const float* __restrict__ W1,
                                              unsigned short* __restrict__ W1T) {
  __shared__ unsigned short tile[32][33];
  int bk = blockIdx.x*32, bn = blockIdx.y*32;
  int tx = threadIdx.x & 31, ty = threadIdx.x >> 5;
  for (int r = ty; r < 32; r += 8) {
    float f = W1[(size_t)(bk + r)*Hdim + bn + tx];
    __hip_bfloat16 h = __float2bfloat16(f);
    tile[r][tx] = *reinterpret_cast<unsigned short*>(&h);
  }
  __syncthreads();
  for (int r = ty; r < 32; r += 8) {
    W1T[(size_t)(bn + r)*Hdim + bk + tx] = tile[tx][r];
  }
}

// ---------------- K2: layer-0 sim; writes mem0_rec, spk_rec, t=0 zeros, bf16 Z ----------------
__global__ __launch_bounds__(256) void k2_sim(const float* __restrict__ NS0,
                                              float* __restrict__ out,
                                              unsigned short* __restrict__ Zb) {
  size_t idx = (size_t)blockIdx.x*256 + threadIdx.x;  // b*H + j
  float ns = NS0[idx];
  float* mem = out + OUT_MEM;
  float* spk = out + OUT_SPK;
  mem[idx] = 0.f;          // mem_rec[0][0]
  mem[BH + idx] = 0.f;     // mem_rec[0][1]
  spk[idx] = 0.f;          // spk_rec[0]
  float m = 0.f;
  for (int t = 1; t < Tdim; ++t) {
    m = __fadd_rn(__fmul_rn(0.9f, m), ns);   // match numpy's mul-then-add rounding
    bool sp = m > 1.0f;                       // mthr > 0
    float z = sp ? 1.f : 0.f;
    if (sp) m = 0.f;                          // reset, recorded post-reset
    mem[(size_t)(2*t)*BH + idx] = m;
    spk[(size_t)t*BH + idx] = z;
    Zb[(size_t)(t-1)*BH + idx] = sp ? (unsigned short)0x3F80 : (unsigned short)0;
  }
}

// ---------------- K3: C[25344,2048] = Z @ W1, fp32 C scattered into mem_rec[t][1] ----------------
// 128x128 tile, BK=32. 2-phase double-buffered LDS (T3 minimum), XOR bank swizzle (T2),
// XCD-bijective grid swizzle with N-fast ordering for A-panel L2 sharing (T1).
#define K3_BK 32
#define NKSTEP (Hdim/K3_BK)   // 64

__global__ __launch_bounds__(256) void k3_gemm(const unsigned short* __restrict__ A,   // Zb [M3][2048]
                                               const unsigned short* __restrict__ BT,  // W1T [2048][2048]
                                               float* __restrict__ mem1) {             // out + OUT_MEM
  __shared__ short As[2][128*K3_BK];  // 2 x 8 KB
  __shared__ short Bs[2][128*K3_BK];
  int tid = threadIdx.x;
  int l = tid & 63;
  int w = tid >> 6;                            // wave 0..3
  int wr = (w >> 1) << 6, wc = (w & 1) << 6;   // 2x2 waves, 64x64 each
  int lr = l & 15, lg = l >> 4;

  // --- T1: XCD-bijective swizzle (3168 = 8*396), N fast within each chunk ---
  int lin = blockIdx.x;
  int wg = (lin & 7)*396 + (lin >> 3);
  int ntile = wg & 15, mtile = wg >> 4;
  size_t gm = (size_t)mtile * 128;
  size_t gn = (size_t)ntile * 128;

  // --- staging: wave w owns chunks {2w,2w+1}; 1 chunk = 16 rows x 32 cols bf16 = 1 KB ---
  // T2 rule-21: LDS dest linear, global SOURCE pre-swizzled with the read-side involution.
  // LDS tile byte pos (r, cb) holds element (r, cb ^ ((r&6)<<3)).
  int c0 = w*2, c1 = w*2 + 1;
  int srow = l >> 2;                                  // row within chunk
  int scol = ((l & 3)*8) ^ (((l >> 2) & 6) << 2);     // swizzled source col (elements)
  const unsigned short* a0 = &A [(gm + c0*16 + srow)*Hdim + scol];
  const unsigned short* a1 = &A [(gm + c1*16 + srow)*Hdim + scol];
  const unsigned short* b0 = &BT[(gn + c0*16 + srow)*Hdim + scol];
  const unsigned short* b1 = &BT[(gn + c1*16 + srow)*Hdim + scol];

  int rdswz = (lr & 6) << 2;   // read-side XOR, in shorts (matches (r&6)<<3 bytes)

  f32x4 acc[4][4] = {};

  // prologue: stage k-step 0 into buf0
  GLD16(a0, &As[0][c0*512]);
  GLD16(a1, &As[0][c1*512]);
  GLD16(b0, &Bs[0][c0*512]);
  GLD16(b1, &Bs[0][c1*512]);
  __syncthreads();

  #pragma unroll 2
  for (int t = 0; t < NKSTEP; ++t) {
    int cur = t & 1;
    if (t + 1 < NKSTEP) {            // stage next k-step into the other buffer (overlaps compute)
      int nxt = cur ^ 1;
      size_t ko = (size_t)(t + 1) * K3_BK;
      GLD16(a0 + ko, &As[nxt][c0*512]);
      GLD16(a1 + ko, &As[nxt][c1*512]);
      GLD16(b0 + ko, &Bs[nxt][c0*512]);
      GLD16(b1 + ko, &Bs[nxt][c1*512]);
    }
    short8 af[4], bfr[4];
    #pragma unroll
    for (int mi = 0; mi < 4; ++mi)
      af[mi] = *reinterpret_cast<const short8*>(&As[cur][(wr + mi*16 + lr)*K3_BK + (lg*8 ^ rdswz)]);
    #pragma unroll
    for (int ni = 0; ni < 4; ++ni)
      bfr[ni] = *reinterpret_cast<const short8*>(&Bs[cur][(wc + ni*16 + lr)*K3_BK + (lg*8 ^ rdswz)]);
    #pragma unroll
    for (int mi = 0; mi < 4; ++mi)
      #pragma unroll
      for (int ni = 0; ni < 4; ++ni)
        acc[mi][ni] = __builtin_amdgcn_mfma_f32_16x16x32_bf16(af[mi], bfr[ni], acc[mi][ni], 0, 0, 0);
    __syncthreads();   // drains vmcnt (next buf landed) + all waves done reading cur
  }

  // epilogue: C/D layout col=lane&15, row=(lane>>4)*4+q; scatter fp32 into mem_rec[t][1]
  #pragma unroll
  for (int mi = 0; mi < 4; ++mi)
    #pragma unroll
    for (int ni = 0; ni < 4; ++ni)
      #pragma unroll
      for (int q = 0; q < 4; ++q) {
        int r = (int)gm + wr + mi*16 + lg*4 + q;   // global M row = (t-1)*256 + b
        int trow = r >> 8, b = r & 255;
        size_t col = gn + wc + ni*16 + lr;
        mem1[(size_t)(2*trow + 3)*BH + (size_t)b*Hdim + col] = acc[mi][ni][q];
      }
}

// ---------------- K4: in-place temporal recurrence over C planes -> mem1_rec + out0 ----------------
__global__ __launch_bounds__(256) void k4_rec(float* __restrict__ out) {
  size_t idx = (size_t)blockIdx.x*256 + threadIdx.x;  // b*H + j
  float* mem = out + OUT_MEM;
  float s = 0.f, m = 0.f;
  for (int t = 1; t < Tdim; ++t) {
    float* p = &mem[(size_t)(2*t + 1)*BH + idx];
    float c = *p;                           // C[t-1][b][j] (fp32, exact from MFMA)
    s = __fadd_rn(__fmul_rn(0.95f, s), c);
    m = __fadd_rn(__fmul_rn(0.9f, m), s);
    *p = m;                                 // mem_rec[t][1]
  }
  out[idx] = m;                             // mem1_rec[-1]
}

extern "C" void kernel_launch(void* const* d_in, const int* in_sizes, int n_in,
                              void* d_out, int out_size, void* d_ws, size_t ws_size,
                              hipStream_t stream) {
  const float* X  = (const float*)d_in[0];
  const float* W0 = (const float*)d_in[1];
  const float* W1 = (const float*)d_in[2];
  float* out = (float*)d_out;
  char* ws = (char*)d_ws;

  float*          ns0 = (float*)ws;                                   // 2 MiB
  unsigned short* w1t = (unsigned short*)(ws + (2ull  << 20));        // 8 MiB
  unsigned short* zb  = (unsigned short*)(ws + (10ull << 20));        // 99 MiB (fits, verified round 1)

  k1_ns0<<<dim3(Bdim/64, Hdim/64), 512, 0, stream>>>(X, W0, ns0);
  k2b_tr<<<dim3(Hdim/32, Hdim/32), 256, 0, stream>>>(W1, w1t);
  k2_sim<<<dim3(BH/256), 256, 0, stream>>>(ns0, out, zb);
  k3_gemm<<<dim3((M3/128)*(Hdim/128)), 256, 0, stream>>>(zb, w1t, out + OUT_MEM);
  k4_rec<<<dim3(BH/256), 256, 0, stream>>>(out);
}